// Round 1
// baseline (514.036 us; speedup 1.0000x reference)
//
#include <hip/hip_runtime.h>

// Problem constants (match reference)
constexpr int NUM_CLASSES = 100000;
constexpr int EMBED_DIM   = 512;
constexpr int BATCH       = 16384;
constexpr int CENTER_ELEMS = NUM_CLASSES * EMBED_DIM;   // 51,200,000 (< 2^31)
constexpr int NSLOTS = 256;                              // loss partial slots in d_ws
constexpr float UPDATE_SCALE = 0.05f;                    // (1 - ALPHA)
constexpr float INV_COUNT = 1.0f / (8388608.0f);         // 1 / (BATCH*EMBED_DIM) = 2^-23 exact

// Kernel 1: copy center_var -> out+1 (dst is 4B-misaligned => scalar dword,
// lane-contiguous so every wave store is a fully-coalesced 256B transaction).
// Also zero the NSLOTS loss partials in workspace (d_ws is poisoned 0xAA).
__global__ void copy_centers_kernel(const float* __restrict__ src,
                                    float* __restrict__ dst,
                                    float* __restrict__ ws_partials) {
    int gid = blockIdx.x * blockDim.x + threadIdx.x;
    if (gid < NSLOTS) ws_partials[gid] = 0.0f;
    int stride = gridDim.x * blockDim.x;
    for (int i = gid; i < CENTER_ELEMS; i += stride) {
        dst[i] = src[i];
    }
}

// Kernel 2: one block per batch row (128 threads = 2 waves, 1 float4/thread).
// Gather center row, delta = 0.05*(f - c), scatter-add into new_centers with
// scalar atomics (duplicate-label safe), wave-reduce squared diff into one of
// NSLOTS workspace accumulators.
__global__ __launch_bounds__(128) void update_kernel(
        const float* __restrict__ features,
        const int*   __restrict__ labels,
        const float* __restrict__ centers,
        float* __restrict__ out,            // out[0]=loss, out+1 = new_centers
        float* __restrict__ ws_partials) {
    const int b = blockIdx.x;
    const int label = labels[b];
    const int t = threadIdx.x;

    const float4 f = ((const float4*)(features + (size_t)b * EMBED_DIM))[t];
    const float4 c = ((const float4*)(centers + (size_t)label * EMBED_DIM))[t];

    float4 d;
    d.x = f.x - c.x;
    d.y = f.y - c.y;
    d.z = f.z - c.z;
    d.w = f.w - c.w;

    // scatter-add the update delta (new_centers row is 4B-misaligned => scalar atomics)
    float* nrow = out + 1 + (size_t)label * EMBED_DIM + (size_t)t * 4;
    atomicAdd(nrow + 0, UPDATE_SCALE * d.x);
    atomicAdd(nrow + 1, UPDATE_SCALE * d.y);
    atomicAdd(nrow + 2, UPDATE_SCALE * d.z);
    atomicAdd(nrow + 3, UPDATE_SCALE * d.w);

    // loss partial: sum of squared diffs, reduced across the 64-lane wave
    float local = d.x * d.x + d.y * d.y + d.z * d.z + d.w * d.w;
    #pragma unroll
    for (int off = 32; off > 0; off >>= 1)
        local += __shfl_down(local, off, 64);

    if ((t & 63) == 0) {
        int wave = t >> 6;                       // 0 or 1
        int slot = (b * 2 + wave) & (NSLOTS - 1);
        atomicAdd(&ws_partials[slot], local);    // ~128 adds/slot: negligible contention
    }
}

// Kernel 3: single wave sums the NSLOTS partials, writes final mean loss.
__global__ __launch_bounds__(64) void finalize_loss_kernel(
        const float* __restrict__ ws_partials,
        float* __restrict__ out) {
    float v = 0.0f;
    #pragma unroll
    for (int k = 0; k < NSLOTS / 64; ++k)
        v += ws_partials[threadIdx.x + k * 64];
    #pragma unroll
    for (int off = 32; off > 0; off >>= 1)
        v += __shfl_down(v, off, 64);
    if (threadIdx.x == 0)
        out[0] = v * INV_COUNT;
}

extern "C" void kernel_launch(void* const* d_in, const int* in_sizes, int n_in,
                              void* d_out, int out_size, void* d_ws, size_t ws_size,
                              hipStream_t stream) {
    const float* features = (const float*)d_in[0];
    const int*   labels   = (const int*)d_in[1];
    const float* centers  = (const float*)d_in[2];
    float* out = (float*)d_out;
    float* ws_partials = (float*)d_ws;

    // 1) new_centers := center_var  (and zero loss partials)
    copy_centers_kernel<<<8192, 256, 0, stream>>>(centers, out + 1, ws_partials);

    // 2) gather + delta + scatter-add + loss partials
    update_kernel<<<BATCH, 128, 0, stream>>>(features, labels, centers, out, ws_partials);

    // 3) final loss reduction
    finalize_loss_kernel<<<1, 64, 0, stream>>>(ws_partials, out);
}

// Round 2
// 389.684 us; speedup vs baseline: 1.3191x; 1.3191x over previous
//
#include <hip/hip_runtime.h>

// Problem constants (match reference)
constexpr int NUM_CLASSES  = 100000;
constexpr int EMBED_DIM    = 512;
constexpr int BATCH        = 16384;
constexpr int CENTER_ELEMS = NUM_CLASSES * EMBED_DIM;   // 51,200,000
constexpr int NSLOTS       = 256;                        // loss partial slots
constexpr float UPDATE_SCALE = 0.05f;                    // (1 - ALPHA)
constexpr float INV_COUNT  = 1.0f / 8388608.0f;          // 1/(BATCH*EMBED_DIM) = 2^-23

// ---------------- new fast path ----------------

// ws layout: counts[NUM_CLASSES] (int), itemof[NUM_CLASSES] (int), partials[NSLOTS] (float)
constexpr size_t WS_NEEDED = (size_t)NUM_CLASSES * 8 + NSLOTS * 4;

__global__ void zero_ws_kernel(int* __restrict__ counts, float* __restrict__ partials) {
    int g = blockIdx.x * blockDim.x + threadIdx.x;
    if (g < NUM_CLASSES) counts[g] = 0;
    if (g < NSLOTS) partials[g] = 0.0f;
}

__global__ void hist_kernel(const int* __restrict__ labels,
                            int* __restrict__ counts,
                            int* __restrict__ itemof) {
    int b = blockIdx.x * blockDim.x + threadIdx.x;
    if (b < BATCH) {
        int l = labels[b];
        atomicAdd(&counts[l], 1);
        itemof[l] = b;   // unique writer when count==1 (the only case we read it)
    }
}

// One block per class row. count==0: copy center. count==1: fold the single
// item's update exactly, no atomics. count>1: copy (dup_update applies deltas).
// Store path: dst row is out+1+c*512 (4B misaligned) -> stage in LDS shifted
// by one element so 127 lanes emit aligned global_store_dwordx4.
__global__ __launch_bounds__(128) void fused_rows_kernel(
        const float* __restrict__ features,
        const float* __restrict__ centers,
        const int*   __restrict__ counts,
        const int*   __restrict__ itemof,
        float* __restrict__ out,            // out[0]=loss, out+1 = new_centers
        float* __restrict__ partials) {
    const int c = blockIdx.x;
    const int t = threadIdx.x;
    const int cnt = counts[c];

    const float4 c4 = ((const float4*)(centers + (size_t)c * EMBED_DIM))[t];
    float4 n4 = c4;

    __shared__ float row[EMBED_DIM];

    if (cnt == 1) {
        const int b = itemof[c];
        const float4 f4 = ((const float4*)(features + (size_t)b * EMBED_DIM))[t];
        float4 d;
        d.x = f4.x - c4.x;
        d.y = f4.y - c4.y;
        d.z = f4.z - c4.z;
        d.w = f4.w - c4.w;
        n4.x = fmaf(UPDATE_SCALE, d.x, c4.x);
        n4.y = fmaf(UPDATE_SCALE, d.y, c4.y);
        n4.z = fmaf(UPDATE_SCALE, d.z, c4.z);
        n4.w = fmaf(UPDATE_SCALE, d.w, c4.w);
        // loss partial vs pre-update center
        float local = d.x * d.x + d.y * d.y + d.z * d.z + d.w * d.w;
        #pragma unroll
        for (int off = 32; off > 0; off >>= 1)
            local += __shfl_down(local, off, 64);
        if ((t & 63) == 0)
            atomicAdd(&partials[(c * 2 + (t >> 6)) & (NSLOTS - 1)], local);
    }

    ((float4*)row)[t] = n4;
    __syncthreads();

    const size_t R = (size_t)c * EMBED_DIM;
    if (t < 127) {
        // out[R+4+4t+k] = newrow[3+4t+k]
        float4 o;
        o.x = row[4 * t + 3];
        o.y = row[4 * t + 4];
        o.z = row[4 * t + 5];
        o.w = row[4 * t + 6];
        ((float4*)(out + R + 4))[t] = o;
    } else {
        out[R + 1] = row[0];
        out[R + 2] = row[1];
        out[R + 3] = row[2];
        out[R + EMBED_DIM] = row[EMBED_DIM - 1];
    }
}

// Duplicate-label items only (~2.5k of 16384): scatter-add via scalar atomics.
__global__ __launch_bounds__(128) void dup_update_kernel(
        const float* __restrict__ features,
        const int*   __restrict__ labels,
        const float* __restrict__ centers,
        const int*   __restrict__ counts,
        float* __restrict__ out,
        float* __restrict__ partials) {
    const int b = blockIdx.x;
    const int l = labels[b];
    if (counts[l] < 2) return;
    const int t = threadIdx.x;

    const float4 f4 = ((const float4*)(features + (size_t)b * EMBED_DIM))[t];
    const float4 c4 = ((const float4*)(centers + (size_t)l * EMBED_DIM))[t];
    float4 d;
    d.x = f4.x - c4.x;
    d.y = f4.y - c4.y;
    d.z = f4.z - c4.z;
    d.w = f4.w - c4.w;

    float* nrow = out + 1 + (size_t)l * EMBED_DIM + (size_t)t * 4;
    atomicAdd(nrow + 0, UPDATE_SCALE * d.x);
    atomicAdd(nrow + 1, UPDATE_SCALE * d.y);
    atomicAdd(nrow + 2, UPDATE_SCALE * d.z);
    atomicAdd(nrow + 3, UPDATE_SCALE * d.w);

    float local = d.x * d.x + d.y * d.y + d.z * d.z + d.w * d.w;
    #pragma unroll
    for (int off = 32; off > 0; off >>= 1)
        local += __shfl_down(local, off, 64);
    if ((t & 63) == 0)
        atomicAdd(&partials[(b * 2 + (t >> 6)) & (NSLOTS - 1)], local);
}

__global__ __launch_bounds__(64) void finalize_loss_kernel(
        const float* __restrict__ partials,
        float* __restrict__ out) {
    float v = 0.0f;
    #pragma unroll
    for (int k = 0; k < NSLOTS / 64; ++k)
        v += partials[threadIdx.x + k * 64];
    #pragma unroll
    for (int off = 32; off > 0; off >>= 1)
        v += __shfl_down(v, off, 64);
    if (threadIdx.x == 0)
        out[0] = v * INV_COUNT;
}

// ---------------- R1 fallback path (proven correct) ----------------

__global__ void copy_centers_kernel(const float* __restrict__ src,
                                    float* __restrict__ dst,
                                    float* __restrict__ ws_partials) {
    int gid = blockIdx.x * blockDim.x + threadIdx.x;
    if (gid < NSLOTS) ws_partials[gid] = 0.0f;
    int stride = gridDim.x * blockDim.x;
    for (int i = gid; i < CENTER_ELEMS; i += stride) dst[i] = src[i];
}

__global__ __launch_bounds__(128) void update_kernel(
        const float* __restrict__ features,
        const int*   __restrict__ labels,
        const float* __restrict__ centers,
        float* __restrict__ out,
        float* __restrict__ ws_partials) {
    const int b = blockIdx.x;
    const int label = labels[b];
    const int t = threadIdx.x;
    const float4 f = ((const float4*)(features + (size_t)b * EMBED_DIM))[t];
    const float4 c = ((const float4*)(centers + (size_t)label * EMBED_DIM))[t];
    float4 d;
    d.x = f.x - c.x; d.y = f.y - c.y; d.z = f.z - c.z; d.w = f.w - c.w;
    float* nrow = out + 1 + (size_t)label * EMBED_DIM + (size_t)t * 4;
    atomicAdd(nrow + 0, UPDATE_SCALE * d.x);
    atomicAdd(nrow + 1, UPDATE_SCALE * d.y);
    atomicAdd(nrow + 2, UPDATE_SCALE * d.z);
    atomicAdd(nrow + 3, UPDATE_SCALE * d.w);
    float local = d.x * d.x + d.y * d.y + d.z * d.z + d.w * d.w;
    #pragma unroll
    for (int off = 32; off > 0; off >>= 1)
        local += __shfl_down(local, off, 64);
    if ((t & 63) == 0)
        atomicAdd(&ws_partials[(b * 2 + (t >> 6)) & (NSLOTS - 1)], local);
}

// ---------------- launcher ----------------

extern "C" void kernel_launch(void* const* d_in, const int* in_sizes, int n_in,
                              void* d_out, int out_size, void* d_ws, size_t ws_size,
                              hipStream_t stream) {
    const float* features = (const float*)d_in[0];
    const int*   labels   = (const int*)d_in[1];
    const float* centers  = (const float*)d_in[2];
    float* out = (float*)d_out;

    if (ws_size >= WS_NEEDED) {
        int*   counts   = (int*)d_ws;
        int*   itemof   = counts + NUM_CLASSES;
        float* partials = (float*)(itemof + NUM_CLASSES);

        zero_ws_kernel<<<(NUM_CLASSES + 255) / 256, 256, 0, stream>>>(counts, partials);
        hist_kernel<<<(BATCH + 255) / 256, 256, 0, stream>>>(labels, counts, itemof);
        fused_rows_kernel<<<NUM_CLASSES, 128, 0, stream>>>(features, centers, counts,
                                                           itemof, out, partials);
        dup_update_kernel<<<BATCH, 128, 0, stream>>>(features, labels, centers,
                                                     counts, out, partials);
        finalize_loss_kernel<<<1, 64, 0, stream>>>(partials, out);
    } else {
        float* partials = (float*)d_ws;
        copy_centers_kernel<<<8192, 256, 0, stream>>>(centers, out + 1, partials);
        update_kernel<<<BATCH, 128, 0, stream>>>(features, labels, centers, out, partials);
        finalize_loss_kernel<<<1, 64, 0, stream>>>(partials, out);
    }
}